// Round 1
// baseline (324.672 us; speedup 1.0000x reference)
//
#include <hip/hip_runtime.h>

// Problem constants (B, T, V, C) = (256, 2048, 32000, 128)
#define B_ 256
#define T_ 2048
#define V_ 32000
#define C_ 128

// b >= TAIL_B is computed by tail_kernel directly from W; its output slab
// doubles as scratch for Wt during K1/K2. 16 b-slabs = 16 MiB >= 16.38 MB Wt.
#define TAIL_B 240

// Native clang vector type — __builtin_nontemporal_* rejects HIP's float4 class.
typedef float v4f __attribute__((ext_vector_type(4)));
typedef int   v4i __attribute__((ext_vector_type(4)));

// K1: Wt[v][c] = W[c][v] + bias[c]  (16.38 MB, written into out's tail slab)
// Standard LDS-tiled 32x32 transpose, +1 pad to kill bank conflicts.
// W is read-once -> nontemporal loads (don't pollute L2; Wt must stay hot).
__global__ __launch_bounds__(256) void transpose_bias_kernel(
    const float* __restrict__ W, const float* __restrict__ bias,
    float* __restrict__ Wt) {
    __shared__ float tile[32][33];
    const int v0 = blockIdx.x * 32;   // V_ / 32 = 1000 blocks in x
    const int c0 = blockIdx.y * 32;   // C_ / 32 = 4 blocks in y
    const int tx = threadIdx.x;       // 0..31
    const int ty = threadIdx.y;       // 0..7
#pragma unroll
    for (int i = 0; i < 4; ++i) {
        const int cl = ty + i * 8;
        tile[cl][tx] = __builtin_nontemporal_load(
            W + (size_t)(c0 + cl) * V_ + v0 + tx);
    }
    __syncthreads();
#pragma unroll
    for (int i = 0; i < 4; ++i) {
        const int vl = ty + i * 8;
        const int c  = c0 + tx;
        Wt[(size_t)(v0 + vl) * C_ + c] = tile[tx][vl] + bias[c];
    }
}

// K2: out[b][c][t] = Wt[idx[b][t]][c], for b in [0, TAIL_B) only.
// Identical structure to the 305-us session-best kernel (kept byte-identical
// on purpose: this round isolates the workspace-poison question).
__global__ __launch_bounds__(256) void gather_kernel(
    const int* __restrict__ idx, const v4f* __restrict__ Wt4,
    float* __restrict__ out) {
    const int b   = blockIdx.y;       // 0..TAIL_B-1
    const int t0  = blockIdx.x * 32;
    const int tid = threadIdx.x;
    const int cq  = tid >> 3;   // 0..31
    const int tg  = tid & 7;    // 0..7
    const int t   = t0 + tg * 4;

    const v4i iv = *(const v4i*)(idx + b * T_ + t);

    const v4f w0 = Wt4[iv.x * (C_ / 4) + cq];
    const v4f w1 = Wt4[iv.y * (C_ / 4) + cq];
    const v4f w2 = Wt4[iv.z * (C_ / 4) + cq];
    const v4f w3 = Wt4[iv.w * (C_ / 4) + cq];

    float* o = out + ((size_t)(b * C_ + cq * 4)) * T_ + t;
    // 4x4 register transpose: component j of w_k -> out[c=4cq+j][t+k]
    __builtin_nontemporal_store((v4f){w0.x, w1.x, w2.x, w3.x}, (v4f*)(o));
    __builtin_nontemporal_store((v4f){w0.y, w1.y, w2.y, w3.y}, (v4f*)(o + T_));
    __builtin_nontemporal_store((v4f){w0.z, w1.z, w2.z, w3.z}, (v4f*)(o + 2 * T_));
    __builtin_nontemporal_store((v4f){w0.w, w1.w, w2.w, w3.w}, (v4f*)(o + 3 * T_));
}

// K3: out[b][c][t] = W[c][idx[b][t]] + bias[c] for b in [TAIL_B, B).
// This slab held Wt during K2; recompute it directly from W (no race: runs
// after K2 on the same stream, reads only W/bias/idx).
// Block = one (b, c) row: idx row staged in LDS (read once, reused),
// W row c (128 KB) is hot in L2 across the 16 b-blocks sharing it,
// writes are a contiguous 8-KB row in 2-KB per-instruction segments.
__global__ __launch_bounds__(256) void tail_kernel(
    const int* __restrict__ idx, const float* __restrict__ W,
    const float* __restrict__ bias, float* __restrict__ out) {
    __shared__ int tIdx[T_];          // 8 KB
    const int c  = blockIdx.x;        // 0..127
    const int b  = TAIL_B + blockIdx.y;  // TAIL_B..255
    const int tid = threadIdx.x;      // 0..255

    const v4i* idx4 = (const v4i*)(idx + (size_t)b * T_);
#pragma unroll
    for (int k = 0; k < 2; ++k) {
        ((v4i*)tIdx)[tid + k * 256] = idx4[tid + k * 256];
    }
    __syncthreads();

    const float* Wr = W + (size_t)c * V_;
    const float bc  = bias[c];
    float* orow = out + ((size_t)b * C_ + c) * T_;

    const int t0 = tid * 8;           // 8 consecutive t per thread
    v4f r0, r1;
    r0.x = Wr[tIdx[t0 + 0]] + bc;
    r0.y = Wr[tIdx[t0 + 1]] + bc;
    r0.z = Wr[tIdx[t0 + 2]] + bc;
    r0.w = Wr[tIdx[t0 + 3]] + bc;
    r1.x = Wr[tIdx[t0 + 4]] + bc;
    r1.y = Wr[tIdx[t0 + 5]] + bc;
    r1.z = Wr[tIdx[t0 + 6]] + bc;
    r1.w = Wr[tIdx[t0 + 7]] + bc;
    __builtin_nontemporal_store(r0, (v4f*)(orow + t0));
    __builtin_nontemporal_store(r1, (v4f*)(orow + t0 + 4));
}

extern "C" void kernel_launch(void* const* d_in, const int* in_sizes, int n_in,
                              void* d_out, int out_size, void* d_ws, size_t ws_size,
                              hipStream_t stream) {
    const int*   idx  = (const int*)d_in[0];    // (B,1,T) int32
    const float* W    = (const float*)d_in[1];  // (C,V) fp32
    const float* bias = (const float*)d_in[2];  // (C,) fp32
    float*       out  = (float*)d_out;          // (B,C,T) fp32

    // Wt lives in the output slab of b >= TAIL_B (written last by tail_kernel).
    // d_ws is deliberately untouched: its 1-GiB re-poison fill (~168 us @ 6.4
    // TB/s, visible as fillBufferAligned in rocprof) is charged to the timed
    // region when the workspace is used.
    float* Wt = out + (size_t)TAIL_B * C_ * T_;   // byte offset 251,658,240 (16B-aligned)

    transpose_bias_kernel<<<dim3(V_ / 32, C_ / 32), dim3(32, 8), 0, stream>>>(
        W, bias, Wt);
    gather_kernel<<<dim3(T_ / 32, TAIL_B), 256, 0, stream>>>(
        idx, (const v4f*)Wt, out);
    tail_kernel<<<dim3(C_, B_ - TAIL_B), 256, 0, stream>>>(
        idx, W, bias, out);
}

// Round 2
// 312.146 us; speedup vs baseline: 1.0401x; 1.0401x over previous
//
#include <hip/hip_runtime.h>

// Problem constants (B, T, V, C) = (256, 2048, 32000, 128)
#define B_ 256
#define T_ 2048
#define V_ 32000
#define C_ 128

// Native clang vector type — __builtin_nontemporal_* rejects HIP's float4 class.
typedef float v4f __attribute__((ext_vector_type(4)));
typedef int   v4i __attribute__((ext_vector_type(4)));

// K1: Wt[v][c] = W[c][v] + bias[c]   (16.4 MB into workspace)
// Standard LDS-tiled 32x32 transpose, +1 pad to kill bank conflicts.
// W is read-once -> nontemporal loads (don't pollute caches; Wt must stay hot).
__global__ __launch_bounds__(256) void transpose_bias_kernel(
    const float* __restrict__ W, const float* __restrict__ bias,
    float* __restrict__ Wt) {
    __shared__ float tile[32][33];
    const int v0 = blockIdx.x * 32;   // V_ / 32 = 1000 blocks in x
    const int c0 = blockIdx.y * 32;   // C_ / 32 = 4 blocks in y
    const int tx = threadIdx.x;       // 0..31
    const int ty = threadIdx.y;       // 0..7
#pragma unroll
    for (int i = 0; i < 4; ++i) {
        const int cl = ty + i * 8;
        tile[cl][tx] = __builtin_nontemporal_load(
            W + (size_t)(c0 + cl) * V_ + v0 + tx);
    }
    __syncthreads();
#pragma unroll
    for (int i = 0; i < 4; ++i) {
        const int vl = ty + i * 8;
        const int c  = c0 + tx;
        Wt[(size_t)(v0 + vl) * C_ + c] = tile[tx][vl] + bias[c];
    }
}

// K2: out[b][c][t] = Wt[idx[b][t]][c]
// v2: TWO b's per block to double per-wave MLP. The gather is latency-bound on
// random 64-B line reads (~0.12 lines/cyc/CU at r0 = ~64 outstanding x ~530 cyc);
// request count and latency are both irreducible, so the lever is issue depth:
// per thread, 2 idx loads + 8 independent row-gathers in flight before the
// first store dependency, vs 1+4 in r0.
//   cq = tid>>3 (0..31): which float4 along C (c = 4*cq .. 4*cq+3)
//   tg = tid&7  (0..7) : which group of 4 consecutive t
// Per wave-instruction: 8 rows x 128-B contiguous segments (full lines).
// Stores NONTEMPORAL: out is write-once; keep 16.4 MB Wt resident in L2/LLC
// instead of thrashing it with 268 MB of write-allocates.
__global__ __launch_bounds__(256) void gather_kernel(
    const int* __restrict__ idx, const v4f* __restrict__ Wt4,
    float* __restrict__ out) {
    const int b0  = blockIdx.y * 2;
    const int t0  = blockIdx.x * 32;
    const int tid = threadIdx.x;
    const int cq  = tid >> 3;   // 0..31
    const int tg  = tid & 7;    // 0..7
    const int t   = t0 + tg * 4;

    const v4i ivA = *(const v4i*)(idx + b0 * T_ + t);
    const v4i ivB = *(const v4i*)(idx + (b0 + 1) * T_ + t);

    const v4f a0 = Wt4[ivA.x * (C_ / 4) + cq];
    const v4f a1 = Wt4[ivA.y * (C_ / 4) + cq];
    const v4f a2 = Wt4[ivA.z * (C_ / 4) + cq];
    const v4f a3 = Wt4[ivA.w * (C_ / 4) + cq];
    const v4f b0v = Wt4[ivB.x * (C_ / 4) + cq];
    const v4f b1v = Wt4[ivB.y * (C_ / 4) + cq];
    const v4f b2v = Wt4[ivB.z * (C_ / 4) + cq];
    const v4f b3v = Wt4[ivB.w * (C_ / 4) + cq];

    float* oA = out + ((size_t)(b0 * C_ + cq * 4)) * T_ + t;
    float* oB = oA + (size_t)C_ * T_;
    // 4x4 register transpose: component j of w_k -> out[c=4cq+j][t+k]
    __builtin_nontemporal_store((v4f){a0.x, a1.x, a2.x, a3.x}, (v4f*)(oA));
    __builtin_nontemporal_store((v4f){a0.y, a1.y, a2.y, a3.y}, (v4f*)(oA + T_));
    __builtin_nontemporal_store((v4f){a0.z, a1.z, a2.z, a3.z}, (v4f*)(oA + 2 * T_));
    __builtin_nontemporal_store((v4f){a0.w, a1.w, a2.w, a3.w}, (v4f*)(oA + 3 * T_));
    __builtin_nontemporal_store((v4f){b0v.x, b1v.x, b2v.x, b3v.x}, (v4f*)(oB));
    __builtin_nontemporal_store((v4f){b0v.y, b1v.y, b2v.y, b3v.y}, (v4f*)(oB + T_));
    __builtin_nontemporal_store((v4f){b0v.z, b1v.z, b2v.z, b3v.z}, (v4f*)(oB + 2 * T_));
    __builtin_nontemporal_store((v4f){b0v.w, b1v.w, b2v.w, b3v.w}, (v4f*)(oB + 3 * T_));
}

// Fallback (only if ws_size can't hold Wt): direct gather from original W layout.
__global__ __launch_bounds__(256) void gather_direct_kernel(
    const int* __restrict__ idx, const float* __restrict__ W,
    const float* __restrict__ bias, float* __restrict__ out) {
    const size_t o = (size_t)blockIdx.x * blockDim.x + threadIdx.x; // over B*C*T/4
    const int T4   = T_ / 4;
    const int t4   = (int)(o % T4);
    const int rest = (int)(o / T4);
    const int c    = rest % C_;
    const int b    = rest / C_;
    const v4i iv   = *(const v4i*)(idx + (size_t)b * T_ + (size_t)t4 * 4);
    const float* Wr = W + (size_t)c * V_;
    const float bc  = bias[c];
    __builtin_nontemporal_store(
        (v4f){Wr[iv.x] + bc, Wr[iv.y] + bc, Wr[iv.z] + bc, Wr[iv.w] + bc},
        ((v4f*)out) + o);
}

extern "C" void kernel_launch(void* const* d_in, const int* in_sizes, int n_in,
                              void* d_out, int out_size, void* d_ws, size_t ws_size,
                              hipStream_t stream) {
    const int*   idx  = (const int*)d_in[0];    // (B,1,T) int32
    const float* W    = (const float*)d_in[1];  // (C,V) fp32
    const float* bias = (const float*)d_in[2];  // (C,) fp32
    float*       out  = (float*)d_out;          // (B,C,T) fp32

    const size_t wt_bytes = (size_t)V_ * C_ * sizeof(float); // 16.4 MB

    // NOTE (r1 finding): the harness re-poisons the 1-GiB workspace with a
    // ~165 us fillBufferAligned INSIDE the timed region UNCONDITIONALLY —
    // avoiding d_ws bought nothing and the W-direct tail cost +20 us.
    // So we use the workspace freely.
    if (ws_size >= wt_bytes) {
        float* Wt = (float*)d_ws;
        transpose_bias_kernel<<<dim3(V_ / 32, C_ / 32), dim3(32, 8), 0, stream>>>(
            W, bias, Wt);
        gather_kernel<<<dim3(T_ / 32, B_ / 2), 256, 0, stream>>>(
            idx, (const v4f*)Wt, out);
    } else {
        const size_t total = (size_t)B_ * C_ * (T_ / 4);
        gather_direct_kernel<<<(unsigned)((total + 255) / 256), 256, 0, stream>>>(
            idx, W, bias, out);
    }
}

// Round 3
// 300.971 us; speedup vs baseline: 1.0787x; 1.0371x over previous
//
#include <hip/hip_runtime.h>

// Problem constants (B, T, V, C) = (256, 2048, 32000, 128)
#define B_ 256
#define T_ 2048
#define V_ 32000
#define C_ 128

// Native clang vector type — __builtin_nontemporal_* rejects HIP's float4 class.
typedef float v4f __attribute__((ext_vector_type(4)));
typedef int   v4i __attribute__((ext_vector_type(4)));

// K1: Wt[v][c] = W[c][v] + bias[c]   (16.4 MB into workspace)
// Standard LDS-tiled 32x32 transpose, +1 pad to kill bank conflicts.
// W is read-once -> nontemporal loads (don't pollute caches; Wt must stay hot).
__global__ __launch_bounds__(256) void transpose_bias_kernel(
    const float* __restrict__ W, const float* __restrict__ bias,
    float* __restrict__ Wt) {
    __shared__ float tile[32][33];
    const int v0 = blockIdx.x * 32;   // V_ / 32 = 1000 blocks in x
    const int c0 = blockIdx.y * 32;   // C_ / 32 = 4 blocks in y
    const int tx = threadIdx.x;       // 0..31
    const int ty = threadIdx.y;       // 0..7
#pragma unroll
    for (int i = 0; i < 4; ++i) {
        const int cl = ty + i * 8;
        tile[cl][tx] = __builtin_nontemporal_load(
            W + (size_t)(c0 + cl) * V_ + v0 + tx);
    }
    __syncthreads();
#pragma unroll
    for (int i = 0; i < 4; ++i) {
        const int vl = ty + i * 8;
        const int c  = c0 + tx;
        Wt[(size_t)(v0 + vl) * C_ + c] = tile[tx][vl] + bias[c];
    }
}

// K2 (r3): XCD-sliced gather. out[b][c][t] = Wt[idx[b][t]][c].
//
// r2 falsified per-wave MLP as the limit -> the per-CU miss queue is
// saturated; throughput = in-flight-lines / latency. Lever: latency.
// Each block owns a 16-column slice of Wt: footprint = 32000 rows x 64 B
// (one aligned line per row) = 2.0 MB, which FITS one XCD's 4-MiB L2.
// slice = blockIdx.x & 7 exploits the round-robin workgroup->XCD dispatch
// so each XCD keeps re-reading only its own 2-MB slice (all-L2-hit gather,
// ~200 cyc instead of ~75% LLC misses at ~600 cyc). If the mapping
// heuristic is wrong this degrades to today's behavior (neutral).
//
// Lane layout (l = lane 0..63): cq = l&3 (float4 within slice), tg = l>>2.
//   gather: 4-lane quads (cq 0..3, fixed row) cover one contiguous 64-B
//           line -> coalesces to a single line request per row.
//   store : fixed cq -> 16 lanes x 16 B = 256-B contiguous segments.
// Stores NONTEMPORAL: out is write-once; don't evict the resident slice.
__global__ __launch_bounds__(256) void gather_sliced_kernel(
    const int* __restrict__ idx, const v4f* __restrict__ Wt4,
    float* __restrict__ out) {
    const int bid   = blockIdx.x;
    const int slice = bid & 7;          // -> XCD (round-robin heuristic)
    const int rest  = bid >> 3;
    const int b     = rest & (B_ - 1);  // 0..255
    const int t0    = (rest >> 8) * 256;

    const int tid = threadIdx.x;
    const int w   = tid >> 6;           // wave 0..3 -> 64-t subrange
    const int l   = tid & 63;
    const int cq  = l & 3;              // float4 within the 16-c slice
    const int tg  = l >> 2;             // 0..15
    const int t   = t0 + w * 64 + tg * 4;

    const v4i iv = *(const v4i*)(idx + b * T_ + t);

    const int cbase = slice * 4 + cq;   // float4 index within row (C_/4 = 32)
    const v4f w0 = Wt4[iv.x * (C_ / 4) + cbase];
    const v4f w1 = Wt4[iv.y * (C_ / 4) + cbase];
    const v4f w2 = Wt4[iv.z * (C_ / 4) + cbase];
    const v4f w3 = Wt4[iv.w * (C_ / 4) + cbase];

    float* o = out + ((size_t)(b * C_ + cbase * 4)) * T_ + t;
    // 4x4 register transpose: component j of w_k -> out[c=4*cbase+j][t+k]
    __builtin_nontemporal_store((v4f){w0.x, w1.x, w2.x, w3.x}, (v4f*)(o));
    __builtin_nontemporal_store((v4f){w0.y, w1.y, w2.y, w3.y}, (v4f*)(o + T_));
    __builtin_nontemporal_store((v4f){w0.z, w1.z, w2.z, w3.z}, (v4f*)(o + 2 * T_));
    __builtin_nontemporal_store((v4f){w0.w, w1.w, w2.w, w3.w}, (v4f*)(o + 3 * T_));
}

// Fallback (only if ws_size can't hold Wt): direct gather from original W layout.
__global__ __launch_bounds__(256) void gather_direct_kernel(
    const int* __restrict__ idx, const float* __restrict__ W,
    const float* __restrict__ bias, float* __restrict__ out) {
    const size_t o = (size_t)blockIdx.x * blockDim.x + threadIdx.x; // over B*C*T/4
    const int T4   = T_ / 4;
    const int t4   = (int)(o % T4);
    const int rest = (int)(o / T4);
    const int c    = rest % C_;
    const int b    = rest / C_;
    const v4i iv   = *(const v4i*)(idx + (size_t)b * T_ + (size_t)t4 * 4);
    const float* Wr = W + (size_t)c * V_;
    const float bc  = bias[c];
    __builtin_nontemporal_store(
        (v4f){Wr[iv.x] + bc, Wr[iv.y] + bc, Wr[iv.z] + bc, Wr[iv.w] + bc},
        ((v4f*)out) + o);
}

extern "C" void kernel_launch(void* const* d_in, const int* in_sizes, int n_in,
                              void* d_out, int out_size, void* d_ws, size_t ws_size,
                              hipStream_t stream) {
    const int*   idx  = (const int*)d_in[0];    // (B,1,T) int32
    const float* W    = (const float*)d_in[1];  // (C,V) fp32
    const float* bias = (const float*)d_in[2];  // (C,) fp32
    float*       out  = (float*)d_out;          // (B,C,T) fp32

    const size_t wt_bytes = (size_t)V_ * C_ * sizeof(float); // 16.4 MB

    // r1 finding: the harness re-poisons the 1-GiB workspace (~165 us
    // fillBufferAligned) inside the timed region UNCONDITIONALLY, so using
    // d_ws is free. r2 finding: per-wave MLP is not the gather's limit.
    if (ws_size >= wt_bytes) {
        float* Wt = (float*)d_ws;
        transpose_bias_kernel<<<dim3(V_ / 32, C_ / 32), dim3(32, 8), 0, stream>>>(
            W, bias, Wt);
        // 8 slices x 256 b x 8 t-tiles = 16384 blocks; slice varies fastest
        // so consecutive workgroups (-> different XCDs) carry different slices.
        gather_sliced_kernel<<<dim3(8 * B_ * (T_ / 256)), 256, 0, stream>>>(
            idx, (const v4f*)Wt, out);
    } else {
        const size_t total = (size_t)B_ * C_ * (T_ / 4);
        gather_direct_kernel<<<(unsigned)((total + 255) / 256), 256, 0, stream>>>(
            idx, W, bias, out);
    }
}